// Round 8
// baseline (1989.806 us; speedup 1.0000x reference)
//
#include <hip/hip_runtime.h>
#include <math.h>

#define NB 32          // MAX_NODES
#define BATCH 16384

// ws layout (16 B, zeroed by hipMemsetAsync): [0]=bce_sum [1]=mask_sum [2]=phys_sum [3]=unused

__device__ __forceinline__ float groupReduceSum(float v) {
    v += __shfl_xor(v, 1, 64);
    v += __shfl_xor(v, 2, 64);
    v += __shfl_xor(v, 4, 64);
    v += __shfl_xor(v, 8, 64);
    v += __shfl_xor(v, 16, 64);
    return v;
}

// One wave per block; 2 matrices per block (lanes 0-31 -> m=0, 32-63 -> m=1).
// LDS = 1 KB only -> occupancy bound moves to waves/VGPR; (64,8) pins VGPR<=64.
__global__ __launch_bounds__(64, 8)
void lap_main(const float* __restrict__ predA, const float* __restrict__ targA,
              const float* __restrict__ nmask, float* __restrict__ out,
              float* __restrict__ ws)
{
    // per-matrix: X=[0,32) P=[32,64) D=[64,96) E=[96,128)  (D/E disjoint from X/P:
    // preserves R7's verified phase-3 barrier structure with no extra sync)
    __shared__ __align__(16) float S[2][128];

    const int t  = threadIdx.x;       // 0..63
    const int m  = t >> 5;            // matrix within block
    const int j  = t & 31;            // row index within matrix
    const int b0 = blockIdx.x * 2;    // first batch index of this block
    const size_t base = (size_t)(b0 + m) * 1024;   // element offset of this matrix

    // ---- phase 1: per-lane row loads (L1/L2-hot), BCE partials, row kept in regs ----
    const float  mr  = nmask[b0 * NB + t];               // own mask value, coalesced
    const float4* pr4 = (const float4*)(predA + base + (size_t)j * NB);
    const float4* tr4 = (const float4*)(targA + base + (size_t)j * NB);
    const float4* nm4 = (const float4*)(nmask + (size_t)(b0 + m) * NB);  // uniform per half

    float r[NB];                                          // own row of pred
    float accB = 0.f, accM = 0.f;
    #pragma unroll
    for (int q = 0; q < 8; ++q) {
        const float4 p  = pr4[q];
        const float4 tg = tr4[q];
        const float4 mc = nm4[q];                         // broadcast within half-wave
        const float bx = -(tg.x * __logf(p.x) + (1.f - tg.x) * __logf(1.f - p.x));
        const float by = -(tg.y * __logf(p.y) + (1.f - tg.y) * __logf(1.f - p.y));
        const float bz = -(tg.z * __logf(p.z) + (1.f - tg.z) * __logf(1.f - p.z));
        const float bw = -(tg.w * __logf(p.w) + (1.f - tg.w) * __logf(1.f - p.w));
        accB += mr * (mc.x * bx + mc.y * by + mc.z * bz + mc.w * bw);
        accM += mr * (mc.x + mc.y + mc.z + mc.w);
        r[4*q+0] = p.x; r[4*q+1] = p.y; r[4*q+2] = p.z; r[4*q+3] = p.w;
    }
    accB = groupReduceSum(accB); accB += __shfl_xor(accB, 32, 64);
    accM = groupReduceSum(accM); accM += __shfl_xor(accM, 32, 64);
    if (t == 0) { atomicAdd(ws + 0, accB); atomicAdd(ws + 1, accM); }  // relaxed, no fence

    // ---- phase 2: M = (L+L^T)/2 in registers; col read coalesced from global ----
    float dsum = 0.f, pdiag = 0.f;
    #pragma unroll
    for (int i = 0; i < NB; ++i) {
        dsum += r[i];
        pdiag = (i == j) ? r[i] : pdiag;                  // r[j] without dynamic indexing
    }
    const float jitter = 1e-5f + (9e-5f / 31.f) * (float)j;
    const float dval = dsum + jitter - pdiag;
    float a[NB];
    #pragma unroll
    for (int i = 0; i < NB; ++i) {
        const float cv = predA[base + (size_t)i * NB + j];  // coalesced across lanes
        const float s  = -0.5f * (r[i] + cv);
        a[i] = (i == j) ? dval : s;
    }

    float* X = &S[m][0];
    float* P = &S[m][NB];

    // ---- phase 3: register-resident Householder, fully unrolled (R7-verified) ----
    float dcap = 0.f, ecap = 0.f;
    #pragma unroll
    for (int k = 0; k < NB - 2; ++k) {
        X[j] = a[k];
        __syncthreads();
        float xv[NB];
        #pragma unroll
        for (int i4 = 0; i4 < 8; ++i4) {
            if (i4 >= ((k + 1) >> 2)) {
                float4 rr = *(const float4*)&X[i4 * 4];
                xv[4*i4+0]=rr.x; xv[4*i4+1]=rr.y; xv[4*i4+2]=rr.z; xv[4*i4+3]=rr.w;
            }
        }
        float sg = 0.f;
        #pragma unroll
        for (int i = 0; i < NB; ++i) if (i > k) sg += xv[i] * xv[i];
        const float x1 = xv[k + 1];
        const float al = (x1 >= 0.f) ? -sqrtf(sg) : sqrtf(sg);
        const float denom = sg - al * x1;
        const float beta = (denom > 1e-30f) ? 1.f / denom : 0.f;
        const float vj = (j > k) ? (a[k] - ((j == k + 1) ? al : 0.f)) : 0.f;
        float dot = 0.f;
        #pragma unroll
        for (int i = 0; i < NB; ++i) if (i > k) dot += a[i] * xv[i];
        const float pj = beta * (dot - al * a[k + 1]);
        P[j] = pj;
        __syncthreads();
        float pv[NB];
        #pragma unroll
        for (int i4 = 0; i4 < 8; ++i4) {
            if (i4 >= (k >> 2)) {
                float4 rr = *(const float4*)&P[i4 * 4];
                pv[4*i4+0]=rr.x; pv[4*i4+1]=rr.y; pv[4*i4+2]=rr.z; pv[4*i4+3]=rr.w;
            }
        }
        float K = 0.f;
        #pragma unroll
        for (int i = 0; i < NB; ++i) if (i > k) {
            const float vi = xv[i] - ((i == k + 1) ? al : 0.f);
            K += vi * pv[i];
        }
        const float c  = 0.5f * beta * K;
        const float wj = pj - c * vj;
        if (j >= k) {
            a[k] -= vj * pv[k];
            #pragma unroll
            for (int i = 0; i < NB; ++i) if (i > k) {
                const float vi = xv[i] - ((i == k + 1) ? al : 0.f);
                const float wi = pv[i] - c * vi;
                a[i] -= vj * wi + wj * vi;
            }
        }
        if (j == k)     dcap = a[k];
        if (j == k + 1) ecap = a[k];
    }
    if (j == NB - 2) dcap = a[NB - 2];
    if (j == NB - 1) { dcap = a[NB - 1]; ecap = a[NB - 2]; }

    // ---- transpose d/e to all lanes (D/E disjoint from X/P -> no pre-sync needed) ----
    float* D = &S[m][2 * NB];
    float* E = &S[m][3 * NB];
    D[j] = dcap;
    if (j > 0) E[j - 1] = ecap;
    else       E[NB - 1] = 0.f;
    __syncthreads();
    float d[NB], e[NB];
    #pragma unroll
    for (int i4 = 0; i4 < 8; ++i4) {
        float4 rd = *(const float4*)&D[i4 * 4];
        float4 re = *(const float4*)&E[i4 * 4];
        d[4*i4+0]=rd.x; d[4*i4+1]=rd.y; d[4*i4+2]=rd.z; d[4*i4+3]=rd.w;
        e[4*i4+0]=re.x; e[4*i4+1]=re.y; e[4*i4+2]=re.z; e[4*i4+3]=re.w;
    }

    // ---- phase 4: Sturm multisection for lambda_2 (32 sigmas/round, 3 rounds) ----
    float lo = 1e30f, hi = -1e30f;
    #pragma unroll
    for (int i = 0; i < NB; ++i) {
        const float rr = ((i > 0) ? fabsf(e[i - 1]) : 0.f) + ((i < NB - 1) ? fabsf(e[i]) : 0.f);
        lo = fminf(lo, d[i] - rr);
        hi = fmaxf(hi, d[i] + rr);
    }
    for (int round = 0; round < 3; ++round) {
        const float step = (hi - lo) * (1.f / 33.f);
        const float sig = lo + step * (float)(j + 1);
        float q = d[0] - sig;
        int cnt = (q < 0.f);
        #pragma unroll
        for (int i = 1; i < NB; ++i) {
            if (fabsf(q) < 1e-20f) q = (q < 0.f) ? -1e-20f : 1e-20f;
            q = (d[i] - sig) - (e[i - 1] * e[i - 1]) / q;
            cnt += (q < 0.f);
        }
        const unsigned long long bal = __ballot(cnt >= 2);
        const unsigned int bits = (unsigned int)(bal >> (m * 32));
        const int jstar = (bits == 0u) ? 32 : __builtin_ctz(bits);
        const float nlo = lo + step * (float)jstar;
        const float nhi = lo + step * (float)(jstar + 1);
        lo = nlo; hi = nhi;
    }
    const float lam2 = 0.5f * (lo + hi);

    if (j == 0) out[2 + b0 + m] = lam2;
    const float ph = fmaxf(0.1f - lam2, 0.f);
    const float ph0 = __shfl(ph, 0, 64);
    const float ph1 = __shfl(ph, 32, 64);
    if (t == 0) atomicAdd(ws + 2, ph0 + ph1);       // relaxed; no fence/ticket (R6 lesson)
}

__global__ __launch_bounds__(64)
void lap_final(float* __restrict__ out, const float* __restrict__ ws) {
    if (threadIdx.x == 0) {
        out[0] = ws[0] / fmaxf(ws[1], 1.f);
        out[1] = ws[2] * (1.f / (float)BATCH);
    }
}

extern "C" void kernel_launch(void* const* d_in, const int* in_sizes, int n_in,
                              void* d_out, int out_size, void* d_ws, size_t ws_size,
                              hipStream_t stream) {
    const float* pred = (const float*)d_in[0];
    const float* targ = (const float*)d_in[1];
    const float* nm   = (const float*)d_in[2];
    float* out = (float*)d_out;
    float* ws  = (float*)d_ws;

    (void)hipMemsetAsync(d_ws, 0, 16, stream);
    hipLaunchKernelGGL(lap_main, dim3(BATCH / 2), dim3(64), 0, stream,
                       pred, targ, nm, out, ws);
    hipLaunchKernelGGL(lap_final, dim3(1), dim3(64), 0, stream, out, ws);
}

// Round 9
// 473.742 us; speedup vs baseline: 4.2002x; 4.2002x over previous
//
#include <hip/hip_runtime.h>
#include <math.h>

#define NB 32          // MAX_NODES
#define BATCH 16384

// ws layout (16 B, zeroed by hipMemsetAsync): [0]=bce_sum [1]=mask_sum [2]=phys_sum [3]=unused

__device__ __forceinline__ float groupReduceSum(float v) {
    v += __shfl_xor(v, 1, 64);
    v += __shfl_xor(v, 2, 64);
    v += __shfl_xor(v, 4, 64);
    v += __shfl_xor(v, 8, 64);
    v += __shfl_xor(v, 16, 64);
    return v;
}

// One wave per block; 2 matrices per block (lanes 0-31 -> m=0, 32-63 -> m=1).
// LDS = 1 KB/block; 1-wave workgroups reach ~25 wg/CU (R8-measured 77% occ).
// NO min-waves hint: R8 proved (64,8) forces VGPR=32 -> 8 GB scratch spill.
__global__ __launch_bounds__(64)
void lap_main(const float* __restrict__ predA, const float* __restrict__ targA,
              const float* __restrict__ nmask, float* __restrict__ out,
              float* __restrict__ ws)
{
    // per-matrix: X=[0,32) P=[32,64) D=[64,96) E=[96,128)
    __shared__ __align__(16) float S[2][128];

    const int t  = threadIdx.x;       // 0..63
    const int m  = t >> 5;            // matrix within block
    const int j  = t & 31;            // row index within matrix
    const int b0 = blockIdx.x * 2;    // first batch index of this block
    const size_t base = (size_t)(b0 + m) * 1024;   // element offset of this matrix

    // ---- phase 1: per-lane row loads, BCE partials, pred row -> a[] directly ----
    const float  mr  = nmask[b0 * NB + t];               // own mask value, coalesced
    const float4* pr4 = (const float4*)(predA + base + (size_t)j * NB);
    const float4* tr4 = (const float4*)(targA + base + (size_t)j * NB);
    const float4* nm4 = (const float4*)(nmask + (size_t)(b0 + m) * NB);  // uniform per half

    float a[NB];                                          // pred row now; matrix row later
    float accB = 0.f, accM = 0.f;
    #pragma unroll
    for (int q = 0; q < 8; ++q) {
        const float4 p  = pr4[q];
        const float4 tg = tr4[q];
        const float4 mc = nm4[q];                         // broadcast within half-wave
        const float bx = -(tg.x * __logf(p.x) + (1.f - tg.x) * __logf(1.f - p.x));
        const float by = -(tg.y * __logf(p.y) + (1.f - tg.y) * __logf(1.f - p.y));
        const float bz = -(tg.z * __logf(p.z) + (1.f - tg.z) * __logf(1.f - p.z));
        const float bw = -(tg.w * __logf(p.w) + (1.f - tg.w) * __logf(1.f - p.w));
        accB += mr * (mc.x * bx + mc.y * by + mc.z * bz + mc.w * bw);
        accM += mr * (mc.x + mc.y + mc.z + mc.w);
        a[4*q+0] = p.x; a[4*q+1] = p.y; a[4*q+2] = p.z; a[4*q+3] = p.w;
    }
    accB = groupReduceSum(accB); accB += __shfl_xor(accB, 32, 64);
    accM = groupReduceSum(accM); accM += __shfl_xor(accM, 32, 64);
    if (t == 0) { atomicAdd(ws + 0, accB); atomicAdd(ws + 1, accM); }  // relaxed, no fence

    // ---- phase 2: M = (L+L^T)/2 in place; col read coalesced from global (L2-hot) ----
    float dsum = 0.f, pdiag = 0.f;
    #pragma unroll
    for (int i = 0; i < NB; ++i) {
        dsum += a[i];
        pdiag = (i == j) ? a[i] : pdiag;                  // a[j] without dynamic indexing
    }
    const float jitter = 1e-5f + (9e-5f / 31.f) * (float)j;
    const float dval = dsum + jitter - pdiag;
    #pragma unroll
    for (int i = 0; i < NB; ++i) {
        const float cv = predA[base + (size_t)i * NB + j];  // coalesced across lanes
        const float s  = -0.5f * (a[i] + cv);
        a[i] = (i == j) ? dval : s;
    }

    float* X = &S[m][0];
    float* P = &S[m][NB];

    // ---- phase 3: register-resident Householder, fully unrolled (R7-verified) ----
    float dcap = 0.f, ecap = 0.f;
    #pragma unroll
    for (int k = 0; k < NB - 2; ++k) {
        X[j] = a[k];
        __syncthreads();
        float xv[NB];
        #pragma unroll
        for (int i4 = 0; i4 < 8; ++i4) {
            if (i4 >= ((k + 1) >> 2)) {
                float4 rr = *(const float4*)&X[i4 * 4];
                xv[4*i4+0]=rr.x; xv[4*i4+1]=rr.y; xv[4*i4+2]=rr.z; xv[4*i4+3]=rr.w;
            }
        }
        float sg = 0.f;
        #pragma unroll
        for (int i = 0; i < NB; ++i) if (i > k) sg += xv[i] * xv[i];
        const float x1 = xv[k + 1];
        const float al = (x1 >= 0.f) ? -sqrtf(sg) : sqrtf(sg);
        const float denom = sg - al * x1;
        const float beta = (denom > 1e-30f) ? 1.f / denom : 0.f;
        const float vj = (j > k) ? (a[k] - ((j == k + 1) ? al : 0.f)) : 0.f;
        float dot = 0.f;
        #pragma unroll
        for (int i = 0; i < NB; ++i) if (i > k) dot += a[i] * xv[i];
        const float pj = beta * (dot - al * a[k + 1]);
        P[j] = pj;
        __syncthreads();
        float pv[NB];
        #pragma unroll
        for (int i4 = 0; i4 < 8; ++i4) {
            if (i4 >= (k >> 2)) {
                float4 rr = *(const float4*)&P[i4 * 4];
                pv[4*i4+0]=rr.x; pv[4*i4+1]=rr.y; pv[4*i4+2]=rr.z; pv[4*i4+3]=rr.w;
            }
        }
        float K = 0.f;
        #pragma unroll
        for (int i = 0; i < NB; ++i) if (i > k) {
            const float vi = xv[i] - ((i == k + 1) ? al : 0.f);
            K += vi * pv[i];
        }
        const float c  = 0.5f * beta * K;
        const float wj = pj - c * vj;
        if (j >= k) {
            a[k] -= vj * pv[k];
            #pragma unroll
            for (int i = 0; i < NB; ++i) if (i > k) {
                const float vi = xv[i] - ((i == k + 1) ? al : 0.f);
                const float wi = pv[i] - c * vi;
                a[i] -= vj * wi + wj * vi;
            }
        }
        if (j == k)     dcap = a[k];
        if (j == k + 1) ecap = a[k];
    }
    if (j == NB - 2) dcap = a[NB - 2];
    if (j == NB - 1) { dcap = a[NB - 1]; ecap = a[NB - 2]; }

    // ---- transpose d/e to all lanes (D/E disjoint from X/P -> no pre-sync needed) ----
    float* D = &S[m][2 * NB];
    float* E = &S[m][3 * NB];
    D[j] = dcap;
    if (j > 0) E[j - 1] = ecap;
    else       E[NB - 1] = 0.f;
    __syncthreads();
    float d[NB], e[NB];
    #pragma unroll
    for (int i4 = 0; i4 < 8; ++i4) {
        float4 rd = *(const float4*)&D[i4 * 4];
        float4 re = *(const float4*)&E[i4 * 4];
        d[4*i4+0]=rd.x; d[4*i4+1]=rd.y; d[4*i4+2]=rd.z; d[4*i4+3]=rd.w;
        e[4*i4+0]=re.x; e[4*i4+1]=re.y; e[4*i4+2]=re.z; e[4*i4+3]=re.w;
    }

    // ---- phase 4: Sturm multisection for lambda_2 (32 sigmas/round, 3 rounds) ----
    float lo = 1e30f, hi = -1e30f;
    #pragma unroll
    for (int i = 0; i < NB; ++i) {
        const float rr = ((i > 0) ? fabsf(e[i - 1]) : 0.f) + ((i < NB - 1) ? fabsf(e[i]) : 0.f);
        lo = fminf(lo, d[i] - rr);
        hi = fmaxf(hi, d[i] + rr);
    }
    for (int round = 0; round < 3; ++round) {
        const float step = (hi - lo) * (1.f / 33.f);
        const float sig = lo + step * (float)(j + 1);
        float q = d[0] - sig;
        int cnt = (q < 0.f);
        #pragma unroll
        for (int i = 1; i < NB; ++i) {
            if (fabsf(q) < 1e-20f) q = (q < 0.f) ? -1e-20f : 1e-20f;
            q = (d[i] - sig) - (e[i - 1] * e[i - 1]) / q;
            cnt += (q < 0.f);
        }
        const unsigned long long bal = __ballot(cnt >= 2);
        const unsigned int bits = (unsigned int)(bal >> (m * 32));
        const int jstar = (bits == 0u) ? 32 : __builtin_ctz(bits);
        const float nlo = lo + step * (float)jstar;
        const float nhi = lo + step * (float)(jstar + 1);
        lo = nlo; hi = nhi;
    }
    const float lam2 = 0.5f * (lo + hi);

    if (j == 0) out[2 + b0 + m] = lam2;
    const float ph = fmaxf(0.1f - lam2, 0.f);
    const float ph0 = __shfl(ph, 0, 64);
    const float ph1 = __shfl(ph, 32, 64);
    if (t == 0) atomicAdd(ws + 2, ph0 + ph1);       // relaxed; no fence/ticket (R6 lesson)
}

__global__ __launch_bounds__(64)
void lap_final(float* __restrict__ out, const float* __restrict__ ws) {
    if (threadIdx.x == 0) {
        out[0] = ws[0] / fmaxf(ws[1], 1.f);
        out[1] = ws[2] * (1.f / (float)BATCH);
    }
}

extern "C" void kernel_launch(void* const* d_in, const int* in_sizes, int n_in,
                              void* d_out, int out_size, void* d_ws, size_t ws_size,
                              hipStream_t stream) {
    const float* pred = (const float*)d_in[0];
    const float* targ = (const float*)d_in[1];
    const float* nm   = (const float*)d_in[2];
    float* out = (float*)d_out;
    float* ws  = (float*)d_ws;

    (void)hipMemsetAsync(d_ws, 0, 16, stream);
    hipLaunchKernelGGL(lap_main, dim3(BATCH / 2), dim3(64), 0, stream,
                       pred, targ, nm, out, ws);
    hipLaunchKernelGGL(lap_final, dim3(1), dim3(64), 0, stream, out, ws);
}

// Round 10
// 460.945 us; speedup vs baseline: 4.3168x; 1.0278x over previous
//
#include <hip/hip_runtime.h>
#include <math.h>

#define NB 32          // MAX_NODES
#define BATCH 16384

// ws layout (16 B, zeroed by hipMemsetAsync): [0]=bce_sum [1]=mask_sum [2]=phys_sum [3]=unused

__device__ __forceinline__ float groupReduceSum(float v) {
    // sum within each 32-lane half of the wave (xor masks <=16 stay in-half)
    v += __shfl_xor(v, 1, 64);
    v += __shfl_xor(v, 2, 64);
    v += __shfl_xor(v, 4, 64);
    v += __shfl_xor(v, 8, 64);
    v += __shfl_xor(v, 16, 64);
    return v;
}

// One wave per block; 2 matrices per block (lanes 0-31 -> m=0, 32-63 -> m=1).
// ZERO LDS, zero barriers: all cross-lane traffic via shfl/bpermute (wave-synchronous).
// NO min-waves hint (R8 lesson: forcing it spills to scratch catastrophically).
__global__ __launch_bounds__(64)
void lap_main(const float* __restrict__ predA, const float* __restrict__ targA,
              const float* __restrict__ nmask, float* __restrict__ out,
              float* __restrict__ ws)
{
    const int t  = threadIdx.x;       // 0..63
    const int m  = t >> 5;            // matrix within block
    const int j  = t & 31;            // row index within matrix
    const int b0 = blockIdx.x * 2;    // first batch index of this block
    const size_t base = (size_t)(b0 + m) * 1024;   // element offset of this matrix

    // ---- phase 1 (R9-verified): per-lane row loads, BCE partials, pred row -> a[] ----
    const float  mr  = nmask[b0 * NB + t];
    const float4* pr4 = (const float4*)(predA + base + (size_t)j * NB);
    const float4* tr4 = (const float4*)(targA + base + (size_t)j * NB);
    const float4* nm4 = (const float4*)(nmask + (size_t)(b0 + m) * NB);

    float a[NB];
    float accB = 0.f, accM = 0.f;
    #pragma unroll
    for (int q = 0; q < 8; ++q) {
        const float4 p  = pr4[q];
        const float4 tg = tr4[q];
        const float4 mc = nm4[q];
        const float bx = -(tg.x * __logf(p.x) + (1.f - tg.x) * __logf(1.f - p.x));
        const float by = -(tg.y * __logf(p.y) + (1.f - tg.y) * __logf(1.f - p.y));
        const float bz = -(tg.z * __logf(p.z) + (1.f - tg.z) * __logf(1.f - p.z));
        const float bw = -(tg.w * __logf(p.w) + (1.f - tg.w) * __logf(1.f - p.w));
        accB += mr * (mc.x * bx + mc.y * by + mc.z * bz + mc.w * bw);
        accM += mr * (mc.x + mc.y + mc.z + mc.w);
        a[4*q+0] = p.x; a[4*q+1] = p.y; a[4*q+2] = p.z; a[4*q+3] = p.w;
    }
    accB = groupReduceSum(accB); accB += __shfl_xor(accB, 32, 64);
    accM = groupReduceSum(accM); accM += __shfl_xor(accM, 32, 64);
    if (t == 0) { atomicAdd(ws + 0, accB); atomicAdd(ws + 1, accM); }  // relaxed, no fence

    // ---- phase 2 (R9-verified): M = (L+L^T)/2 in place; col coalesced from global ----
    float dsum = 0.f, pdiag = 0.f;
    #pragma unroll
    for (int i = 0; i < NB; ++i) {
        dsum += a[i];
        pdiag = (i == j) ? a[i] : pdiag;
    }
    const float jitter = 1e-5f + (9e-5f / 31.f) * (float)j;
    const float dval = dsum + jitter - pdiag;
    #pragma unroll
    for (int i = 0; i < NB; ++i) {
        const float cv = predA[base + (size_t)i * NB + j];  // coalesced across lanes
        const float s  = -0.5f * (a[i] + cv);
        a[i] = (i == j) ? dval : s;
    }

    // ---- phase 3: Householder, barrier-free via shuffles, tree reductions ----
    // Column k lives distributed: lane i holds a[k]. Broadcast via __shfl(.,i,32).
    // sg = sum_{i>k} a_i[k]^2 and K = v.p are lane-distributed -> shuffle-reduce.
    float dcap = 0.f, ecap = 0.f;
    #pragma unroll
    for (int k = 0; k < NB - 2; ++k) {
        const float colk = a[k];
        const float sg = groupReduceSum((j > k) ? colk * colk : 0.f);
        float xv[NB];                                 // v_i for i>k (after -al fixup)
        #pragma unroll
        for (int i = 0; i < NB; ++i) xv[i] = (i > k) ? __shfl(colk, i, 32) : 0.f;
        const float x1 = xv[k + 1];
        const float al = (x1 >= 0.f) ? -sqrtf(sg) : sqrtf(sg);
        const float denom = sg - al * x1;
        const float beta = (denom > 1e-30f) ? __builtin_amdgcn_rcpf(denom) : 0.f;
        xv[k + 1] = x1 - al;                          // xv := v
        const float vj = (j > k) ? (colk - ((j == k + 1) ? al : 0.f)) : 0.f;
        // dot = a_row . v  (8-accumulator pairwise tree, depth ~28 cyc)
        float acc[8];
        #pragma unroll
        for (int u = 0; u < 8; ++u) acc[u] = 0.f;
        #pragma unroll
        for (int i = 0; i < NB; ++i) if (i > k) acc[i & 7] += a[i] * xv[i];
        const float dot = ((acc[0] + acc[4]) + (acc[2] + acc[6]))
                        + ((acc[1] + acc[5]) + (acc[3] + acc[7]));
        const float pj = beta * dot;                  // p_j = beta * (A v)_j
        const float K  = groupReduceSum(vj * pj);     // v.p (vj=0 for j<=k)
        const float c  = 0.5f * beta * K;
        const float s2 = pj - 2.f * c * vj;           // = w_j - c*v_j
        float pv[NB];
        #pragma unroll
        for (int i = 0; i < NB; ++i) pv[i] = (i >= k) ? __shfl(pj, i, 32) : 0.f;
        if (j >= k) {                                 // rows <k frozen (finalized)
            a[k] -= vj * pv[k];                       // i=k: v_k=0, w_k=p_k
            #pragma unroll
            for (int i = 0; i < NB; ++i) if (i > k)
                a[i] -= vj * pv[i] + s2 * xv[i];      // -= v_j*w_i + w_j*v_i (folded)
        }
        if (j == k)     dcap = a[k];                  // d_k final after step k
        if (j == k + 1) ecap = a[k];                  // e_k = A[k+1][k]
    }
    if (j == NB - 2) dcap = a[NB - 2];
    if (j == NB - 1) { dcap = a[NB - 1]; ecap = a[NB - 2]; }

    // ---- gather d/e to all lanes via shuffles (no LDS) ----
    float d[NB], e[NB];
    #pragma unroll
    for (int i = 0; i < NB; ++i) d[i] = __shfl(dcap, i, 32);
    #pragma unroll
    for (int i = 0; i < NB - 1; ++i) e[i] = __shfl(ecap, i + 1, 32);
    e[NB - 1] = 0.f;

    // ---- phase 4: Sturm multisection (32 sigmas/round, 3 rounds), rcp-based ----
    float e2[NB];
    #pragma unroll
    for (int i = 0; i < NB; ++i) e2[i] = e[i] * e[i];
    float lo = 1e30f, hi = -1e30f;
    #pragma unroll
    for (int i = 0; i < NB; ++i) {
        const float rr = ((i > 0) ? fabsf(e[i - 1]) : 0.f) + ((i < NB - 1) ? fabsf(e[i]) : 0.f);
        lo = fminf(lo, d[i] - rr);
        hi = fmaxf(hi, d[i] + rr);
    }
    for (int round = 0; round < 3; ++round) {
        const float step = (hi - lo) * (1.f / 33.f);
        const float sig = lo + step * (float)(j + 1);
        float q = d[0] - sig;
        int cnt = (q < 0.f);
        #pragma unroll
        for (int i = 1; i < NB; ++i) {
            if (fabsf(q) < 1e-20f) q = (q < 0.f) ? -1e-20f : 1e-20f;
            q = (d[i] - sig) - e2[i - 1] * __builtin_amdgcn_rcpf(q);
            cnt += (q < 0.f);
        }
        const unsigned long long bal = __ballot(cnt >= 2);
        const unsigned int bits = (unsigned int)(bal >> (m * 32));
        const int jstar = (bits == 0u) ? 32 : __builtin_ctz(bits);
        const float nlo = lo + step * (float)jstar;
        const float nhi = lo + step * (float)(jstar + 1);
        lo = nlo; hi = nhi;
    }
    const float lam2 = 0.5f * (lo + hi);

    if (j == 0) out[2 + b0 + m] = lam2;
    const float ph = fmaxf(0.1f - lam2, 0.f);
    const float ph0 = __shfl(ph, 0, 64);
    const float ph1 = __shfl(ph, 32, 64);
    if (t == 0) atomicAdd(ws + 2, ph0 + ph1);        // relaxed; no fence/ticket (R6 lesson)
}

__global__ __launch_bounds__(64)
void lap_final(float* __restrict__ out, const float* __restrict__ ws) {
    if (threadIdx.x == 0) {
        out[0] = ws[0] / fmaxf(ws[1], 1.f);
        out[1] = ws[2] * (1.f / (float)BATCH);
    }
}

extern "C" void kernel_launch(void* const* d_in, const int* in_sizes, int n_in,
                              void* d_out, int out_size, void* d_ws, size_t ws_size,
                              hipStream_t stream) {
    const float* pred = (const float*)d_in[0];
    const float* targ = (const float*)d_in[1];
    const float* nm   = (const float*)d_in[2];
    float* out = (float*)d_out;
    float* ws  = (float*)d_ws;

    (void)hipMemsetAsync(d_ws, 0, 16, stream);
    hipLaunchKernelGGL(lap_main, dim3(BATCH / 2), dim3(64), 0, stream,
                       pred, targ, nm, out, ws);
    hipLaunchKernelGGL(lap_final, dim3(1), dim3(64), 0, stream, out, ws);
}